// Round 3
// baseline (348.697 us; speedup 1.0000x reference)
//
#include <hip/hip_runtime.h>
#include <math.h>

typedef __attribute__((ext_vector_type(8))) short bf16x8;
typedef __attribute__((ext_vector_type(4))) float f32x4;
typedef __attribute__((ext_vector_type(4))) unsigned int u32x4;

__device__ __forceinline__ unsigned f2bf(float f) {
    union { float f; unsigned u; } v; v.f = f;
    return (v.u + 0x7FFFu + ((v.u >> 16) & 1u)) >> 16;   // RTNE bf16
}

// Build conv kernel in bf16, layout Kb[tap][o][i] (i contiguous), taps 0..125
// with tap 125 all-zero (pad for tap-pairing). Self-interaction folded into
// center tap (62), x10 since out = 0.1*conv_total.
__global__ __launch_bounds__(256) void build_K(
    const float* __restrict__ w_lin0,
    const float* __restrict__ w_lin1,
    const float* __restrict__ tp_weight,
    unsigned short* __restrict__ Kb)
{
    const int tid = (int)threadIdx.x;
    const int tap = (int)blockIdx.x;            // 0..125
    if (tap == 125) {
        for (int n = tid; n < 4096; n += 256) Kb[125 * 4096 + n] = 0;
        return;
    }
    const int i1 = tap / 25, i2 = (tap / 5) % 5, i3 = tap % 5;
    const float X = -1.0f + 0.5f * (float)i1;
    const float Y = -1.0f + 0.5f * (float)i2;
    const float Z = -1.0f + 0.5f * (float)i3;
    const float d = sqrtf(X*X + Y*Y + Z*Z);
    const float dinv = 1.0f / fmaxf(d, 1e-12f);
    const float vx = X * dinv, vy = Y * dinv, vz = Z * dinv;
    const float r2 = vx*vx + vy*vy + vz*vz;

    __shared__ float wsh[1280];
    __shared__ float y1s[3];
    __shared__ float Qs[9];

    if (tid == 0) {
        const float s3 = 1.7320508075688772f;
        const float s15 = 3.872983346207417f;
        y1s[0] = s3 * vy; y1s[1] = s3 * vz; y1s[2] = s3 * vx;
        float y2v0 = s15 * vx * vy;
        float y2v1 = s15 * vy * vz;
        float y2v2 = 1.118033988749895f * (3.0f * vz * vz - r2);
        float y2v3 = s15 * vx * vz;
        float y2v4 = 1.9364916731037085f * (vx * vx - vy * vy);
        const float INV10 = 0.31622776601683794f;
        const float INV30 = 0.18257418583505536f;
        Qs[0] = -y2v2 * INV30 - y2v4 * INV10;
        Qs[4] =  2.0f * y2v2 * INV30;
        Qs[8] = -y2v2 * INV30 + y2v4 * INV10;
        Qs[1] = Qs[3] = y2v1 * INV10;
        Qs[2] = Qs[6] = y2v0 * INV10;
        Qs[5] = Qs[7] = y2v3 * INV10;
    }

    float emb[5];
    #pragma unroll
    for (int e = 0; e < 5; ++e) {
        float t = (d - 0.25f * (float)e) * 4.0f;
        emb[e] = expf(-t * t) * (1.0f / 1.12f);
    }
    const float scale = cosf(3.14159265358979323846f * d) / 11.180339887498949f;

    for (int j = tid; j < 1280; j += 256) {
        float s = 0.0f;
        #pragma unroll
        for (int e = 0; e < 5; ++e) s += emb[e] * tp_weight[e * 1280 + j];
        wsh[j] = scale * s;
    }
    __syncthreads();

    const float F0   = 0.17677669529663687f;
    const float F1   = 0.25f;
    const float F0S3 = 0.10206207261596574f;
    const float F1S3 = 0.14433756729740646f;

    #pragma unroll 1
    for (int n = 0; n < 16; ++n) {
        int e = n * 256 + tid;
        int o = e & 63, i = e >> 6;
        float Kv;
        if (o < 16) {
            if (i < 16) {
                Kv = F0 * wsh[0 * 256 + i * 16 + o];
            } else {
                int u = (i - 16) / 3, a = (i - 16) % 3;
                Kv = F0S3 * y1s[a] * wsh[3 * 256 + u * 16 + o];
            }
        } else {
            int wcol = (o - 16) / 3, c = (o - 16) % 3;
            if (i < 16) {
                Kv = F1S3 * y1s[c] * wsh[1 * 256 + i * 16 + wcol];
            } else {
                int u = (i - 16) / 3, a = (i - 16) % 3;
                Kv = F1 * Qs[a * 3 + c] * wsh[4 * 256 + u * 16 + wcol];
                if (a == c) Kv += F1S3 * wsh[2 * 256 + u * 16 + wcol];
            }
        }
        if (tap == 62) {
            if (o < 16) {
                if (i < 16) Kv += 2.5f * w_lin0[i * 16 + o];
            } else if (i >= 16) {
                int v = (o - 16) / 3, m = (o - 16) % 3;
                int u = (i - 16) / 3, a = (i - 16) % 3;
                if (a == m) Kv += 2.5f * w_lin1[u * 16 + v];
            }
        }
        Kb[(tap * 64 + o) * 64 + i] = (unsigned short)f2bf(Kv);
    }
}

// Pre-pass: x fp32 [b][c][32^3] -> xbz bf16 channel-last [b][pos][64ch],
// preceded by a 128B zero page (for OOB halo lanes).
__global__ __launch_bounds__(256) void to_blc(
    const float* __restrict__ x,
    unsigned short* __restrict__ xbz)
{
    const int tid = (int)threadIdx.x, blk = (int)blockIdx.x;
    if (blk == 0 && tid < 64) xbz[tid] = 0;          // zero page
    const int p = blk * 256 + tid;                   // 0..131071
    const int b = p >> 15, pos = p & 32767;
    const float* xp = x + ((size_t)b << 21) + pos;
    unsigned short* op = xbz + 64 + (size_t)p * 64;
    #pragma unroll
    for (int cg = 0; cg < 8; ++cg) {
        u32x4 dv;
        #pragma unroll
        for (int jj = 0; jj < 4; ++jj) {
            float f0 = xp[((size_t)(cg * 8 + 2 * jj)) << 15];
            float f1 = xp[((size_t)(cg * 8 + 2 * jj + 1)) << 15];
            dv[jj] = f2bf(f0) | (f2bf(f1) << 16);
        }
        *(u32x4*)(op + cg * 8) = dv;
    }
}

// Implicit-GEMM conv via MFMA 16x16x32 bf16.
// Block: 256 thr = 4 waves; tile = 4z x 8y x 8x = 256 pos, all 64 o.
// LDS: halo tile [8z][12y][12x] x 32B (16ch bf16), XOR-16 swizzle on (x&4),
// staged via global_load_lds from channel-last bf16 (pre-swizzled source).
// Tap loop fully unrolled, compile-time offsets, A ping-pong prefetch.
__global__ __launch_bounds__(256, 2) void conv_mfma(
    const unsigned short* __restrict__ xbz,
    const unsigned short* __restrict__ Kb,
    float* __restrict__ out)
{
    __shared__ __align__(16) char xs[36864];

    const int tid = (int)threadIdx.x;
    const int blk = (int)blockIdx.x;
    const int xt = blk & 3, yt = (blk >> 2) & 3, zt = (blk >> 4) & 7, b = blk >> 7;
    const int lane = tid & 63, wv = tid >> 6;
    const int r = lane & 15, g = lane >> 4;
    const int thalf = g >> 1, chslot = g & 1;
    const bool thv = (thalf != 0);

    // ---- staging source offsets (9 chunks/thread), computed once ----
    unsigned srcOff[9];
    {
        const int gz0 = zt * 4 - 2, gy0 = yt * 8 - 2, gx0 = xt * 8 - 2;
        #pragma unroll
        for (int i = 0; i < 9; ++i) {
            int pos = wv * 288 + i * 32 + (lane >> 1);     // 0..1151
            int hz = pos / 144; int rem = pos - hz * 144;
            int hy = rem / 12;  int hx = rem - hy * 12;
            int gz = gz0 + hz, gy = gy0 + hy, gx = gx0 + hx;
            bool ok = ((unsigned)gz < 32u) && ((unsigned)gy < 32u) && ((unsigned)gx < 32u);
            int pg = (gz << 10) + (gy << 5) + gx;
            unsigned chs = (unsigned)((lane & 1) ^ ((hx >> 2) & 1));  // swizzle-inverse
            srcOff[i] = ok ? (unsigned)(128 + (((b << 15) + pg) << 7) + chs * 16)
                           : (unsigned)((lane & 1) * 16);             // zero page
        }
    }

    // ---- per-lane LDS read bases for dx=0..4 (XOR-swizzled) ----
    int axd[5];
    #pragma unroll
    for (int dx = 0; dx < 5; ++dx) {
        int xx = (r & 7) + dx;
        int byte = wv * 4608 + (r >> 3) * 384 + xx * 32 + chslot * 16;
        axd[dx] = byte ^ ((xx & 4) << 2);
    }

    const char* kbl = (const char*)Kb + r * 128 + thalf * 8192 + chslot * 16;

    f32x4 acc[4][4];
    #pragma unroll
    for (int i = 0; i < 4; ++i)
        #pragma unroll
        for (int j = 0; j < 4; ++j) acc[i][j] = (f32x4)0.0f;

    #pragma unroll 1
    for (int stage = 0; stage < 4; ++stage) {
        if (stage) __syncthreads();                // prior reads done
        const char* ldsb = &xs[wv * 9216];
        #pragma unroll
        for (int i = 0; i < 9; ++i) {
            const char* src = (const char*)xbz + srcOff[i] + stage * 32;
            __builtin_amdgcn_global_load_lds(
                (const __attribute__((address_space(1))) unsigned int*)src,
                (__attribute__((address_space(3))) unsigned int*)(ldsb + i * 1024),
                16, 0, 0);
        }
        const char* kbs = kbl + stage * 32;
        bf16x8 Ab[2][4];
        #pragma unroll
        for (int mo = 0; mo < 4; ++mo)
            Ab[0][mo] = *(const bf16x8*)(kbs + mo * 2048);
        __syncthreads();                           // staging complete

        #pragma unroll
        for (int P = 0; P < 63; ++P) {
            const int tA = 2 * P;
            const int tB = (2 * P + 1 == 125) ? 124 : 2 * P + 1;  // pad tap aliases 124
            const int cA = (tA / 25) * 4608 + ((tA / 5) % 5) * 384, dxA = tA % 5;
            const int cB = (tB / 25) * 4608 + ((tB / 5) % 5) * 384, dxB = tB % 5;
            int va = axd[dxA] + cA;
            int vb = axd[dxB] + cB;
            int ad = thv ? vb : va;
            if (P < 62) {
                #pragma unroll
                for (int mo = 0; mo < 4; ++mo)
                    Ab[(P + 1) & 1][mo] =
                        *(const bf16x8*)(kbs + (P + 1) * 16384 + mo * 2048);
            }
            bf16x8 xf[4];
            #pragma unroll
            for (int np = 0; np < 4; ++np)
                xf[np] = *(const bf16x8*)&xs[ad + np * 768];
            #pragma unroll
            for (int mo = 0; mo < 4; ++mo)
                #pragma unroll
                for (int np = 0; np < 4; ++np)
                    acc[mo][np] = __builtin_amdgcn_mfma_f32_16x16x32_bf16(
                        Ab[P & 1][mo], xf[np], acc[mo][np], 0, 0, 0);
        }
    }

    // epilogue: D row = o-in-tile = g*4+reg, col = pos-in-tile = r
    const int oz = zt * 4 + wv;
    #pragma unroll
    for (int mo = 0; mo < 4; ++mo) {
        #pragma unroll
        for (int reg = 0; reg < 4; ++reg) {
            int o = mo * 16 + g * 4 + reg;
            float* op = out + (((size_t)(b * 64 + o)) << 15) + (oz << 10);
            #pragma unroll
            for (int np = 0; np < 4; ++np) {
                int ly = np * 2 + (r >> 3), lx = r & 7;
                op[((yt * 8 + ly) << 5) + (xt * 8 + lx)] = 0.1f * acc[mo][np][reg];
            }
        }
    }
}

extern "C" void kernel_launch(void* const* d_in, const int* in_sizes, int n_in,
                              void* d_out, int out_size, void* d_ws, size_t ws_size,
                              hipStream_t stream) {
    const float* x       = (const float*)d_in[0];
    const float* w_lin0  = (const float*)d_in[1];
    const float* w_lin1  = (const float*)d_in[2];
    const float* tp      = (const float*)d_in[3];
    unsigned short* Kb  = (unsigned short*)d_ws;                        // ~1.03 MB
    unsigned short* xbz = (unsigned short*)((char*)d_ws + (2u << 20));  // 128B zeros + 16.8MB bf16 x
    float* out = (float*)d_out;

    build_K<<<126, 256, 0, stream>>>(w_lin0, w_lin1, tp, Kb);
    to_blc<<<512, 256, 0, stream>>>(x, xbz);
    conv_mfma<<<512, 256, 0, stream>>>(xbz, Kb, out);
}

// Round 5
// 340.847 us; speedup vs baseline: 1.0230x; 1.0230x over previous
//
#include <hip/hip_runtime.h>
#include <math.h>

typedef __attribute__((ext_vector_type(8))) short bf16x8;
typedef __attribute__((ext_vector_type(4))) float f32x4;
typedef __attribute__((ext_vector_type(4))) unsigned int u32x4;

__device__ __forceinline__ unsigned f2bf(float f) {
    union { float f; unsigned u; } v; v.f = f;
    return (v.u + 0x7FFFu + ((v.u >> 16) & 1u)) >> 16;   // RTNE bf16
}

// Build conv kernel in bf16, layout Kb[tap][o][i] (i contiguous), taps 0..125
// with tap 125 all-zero (pad for tap-pairing). Self-interaction folded into
// center tap (62), x10 since out = 0.1*conv_total.
__global__ __launch_bounds__(256) void build_K(
    const float* __restrict__ w_lin0,
    const float* __restrict__ w_lin1,
    const float* __restrict__ tp_weight,
    unsigned short* __restrict__ Kb)
{
    const int tid = (int)threadIdx.x;
    const int tap = (int)blockIdx.x;            // 0..125
    if (tap == 125) {
        for (int n = tid; n < 4096; n += 256) Kb[125 * 4096 + n] = 0;
        return;
    }
    const int i1 = tap / 25, i2 = (tap / 5) % 5, i3 = tap % 5;
    const float X = -1.0f + 0.5f * (float)i1;
    const float Y = -1.0f + 0.5f * (float)i2;
    const float Z = -1.0f + 0.5f * (float)i3;
    const float d = sqrtf(X*X + Y*Y + Z*Z);
    const float dinv = 1.0f / fmaxf(d, 1e-12f);
    const float vx = X * dinv, vy = Y * dinv, vz = Z * dinv;
    const float r2 = vx*vx + vy*vy + vz*vz;

    __shared__ float wsh[1280];
    __shared__ float y1s[3];
    __shared__ float Qs[9];

    if (tid == 0) {
        const float s3 = 1.7320508075688772f;
        const float s15 = 3.872983346207417f;
        y1s[0] = s3 * vy; y1s[1] = s3 * vz; y1s[2] = s3 * vx;
        float y2v0 = s15 * vx * vy;
        float y2v1 = s15 * vy * vz;
        float y2v2 = 1.118033988749895f * (3.0f * vz * vz - r2);
        float y2v3 = s15 * vx * vz;
        float y2v4 = 1.9364916731037085f * (vx * vx - vy * vy);
        const float INV10 = 0.31622776601683794f;
        const float INV30 = 0.18257418583505536f;
        Qs[0] = -y2v2 * INV30 - y2v4 * INV10;
        Qs[4] =  2.0f * y2v2 * INV30;
        Qs[8] = -y2v2 * INV30 + y2v4 * INV10;
        Qs[1] = Qs[3] = y2v1 * INV10;
        Qs[2] = Qs[6] = y2v0 * INV10;
        Qs[5] = Qs[7] = y2v3 * INV10;
    }

    float emb[5];
    #pragma unroll
    for (int e = 0; e < 5; ++e) {
        float t = (d - 0.25f * (float)e) * 4.0f;
        emb[e] = expf(-t * t) * (1.0f / 1.12f);
    }
    const float scale = cosf(3.14159265358979323846f * d) / 11.180339887498949f;

    for (int j = tid; j < 1280; j += 256) {
        float s = 0.0f;
        #pragma unroll
        for (int e = 0; e < 5; ++e) s += emb[e] * tp_weight[e * 1280 + j];
        wsh[j] = scale * s;
    }
    __syncthreads();

    const float F0   = 0.17677669529663687f;
    const float F1   = 0.25f;
    const float F0S3 = 0.10206207261596574f;
    const float F1S3 = 0.14433756729740646f;

    #pragma unroll 1
    for (int n = 0; n < 16; ++n) {
        int e = n * 256 + tid;
        int o = e & 63, i = e >> 6;
        float Kv;
        if (o < 16) {
            if (i < 16) {
                Kv = F0 * wsh[0 * 256 + i * 16 + o];
            } else {
                int u = (i - 16) / 3, a = (i - 16) % 3;
                Kv = F0S3 * y1s[a] * wsh[3 * 256 + u * 16 + o];
            }
        } else {
            int wcol = (o - 16) / 3, c = (o - 16) % 3;
            if (i < 16) {
                Kv = F1S3 * y1s[c] * wsh[1 * 256 + i * 16 + wcol];
            } else {
                int u = (i - 16) / 3, a = (i - 16) % 3;
                Kv = F1 * Qs[a * 3 + c] * wsh[4 * 256 + u * 16 + wcol];
                if (a == c) Kv += F1S3 * wsh[2 * 256 + u * 16 + wcol];
            }
        }
        if (tap == 62) {
            if (o < 16) {
                if (i < 16) Kv += 2.5f * w_lin0[i * 16 + o];
            } else if (i >= 16) {
                int v = (o - 16) / 3, m = (o - 16) % 3;
                int u = (i - 16) / 3, a = (i - 16) % 3;
                if (a == m) Kv += 2.5f * w_lin1[u * 16 + v];
            }
        }
        Kb[(tap * 64 + o) * 64 + i] = (unsigned short)f2bf(Kv);
    }
}

// Pre-pass: x fp32 [b][c][32^3] -> xbz bf16 channel-last [b][pos][64ch],
// preceded by a 128B zero page (for OOB halo lanes).
__global__ __launch_bounds__(256) void to_blc(
    const float* __restrict__ x,
    unsigned short* __restrict__ xbz)
{
    const int tid = (int)threadIdx.x, blk = (int)blockIdx.x;
    if (blk == 0 && tid < 64) xbz[tid] = 0;          // zero page
    const int p = blk * 256 + tid;                   // 0..131071
    const int b = p >> 15, pos = p & 32767;
    const float* xp = x + ((size_t)b << 21) + pos;
    unsigned short* op = xbz + 64 + (size_t)p * 64;
    #pragma unroll
    for (int cg = 0; cg < 8; ++cg) {
        u32x4 dv;
        #pragma unroll
        for (int jj = 0; jj < 4; ++jj) {
            float f0 = xp[((size_t)(cg * 8 + 2 * jj)) << 15];
            float f1 = xp[((size_t)(cg * 8 + 2 * jj + 1)) << 15];
            dv[jj] = f2bf(f0) | (f2bf(f1) << 16);
        }
        *(u32x4*)(op + cg * 8) = dv;
    }
}

// Implicit-GEMM conv via MFMA 16x16x32 bf16.
// Block: 256 thr = 4 waves; tile = 4z x 8y x 8x = 256 pos, all 64 o.
// LDS: double-buffered halo tile [8z][12y][12x] x 32B (16ch bf16),
// XOR-16 swizzle on (x&4), staged via global_load_lds (pre-swizzled source)
// for stage s+1 while computing stage s -> one barrier per stage.
// Tap loop fully unrolled; Kb A-fragments ring: 4 slots, prefetch distance 3
// (distance 4 aliased the consuming slot -> round-4 corruption).
__global__ __launch_bounds__(256, 2) void conv_mfma(
    const unsigned short* __restrict__ xbz,
    const unsigned short* __restrict__ Kb,
    float* __restrict__ out)
{
    __shared__ __align__(16) char xs[73728];   // 2 x 36864

    const int tid = (int)threadIdx.x;
    const int blk = (int)blockIdx.x;
    const int xt = blk & 3, yt = (blk >> 2) & 3, zt = (blk >> 4) & 7, b = blk >> 7;
    const int lane = tid & 63, wv = tid >> 6;
    const int r = lane & 15, g = lane >> 4;
    const int thalf = g >> 1, chslot = g & 1;
    const bool thv = (thalf != 0);

    // ---- staging source offsets (9 chunks/thread), computed once ----
    unsigned srcOff[9];
    {
        const int gz0 = zt * 4 - 2, gy0 = yt * 8 - 2, gx0 = xt * 8 - 2;
        #pragma unroll
        for (int i = 0; i < 9; ++i) {
            int pos = wv * 288 + i * 32 + (lane >> 1);     // 0..1151
            int hz = pos / 144; int rem = pos - hz * 144;
            int hy = rem / 12;  int hx = rem - hy * 12;
            int gz = gz0 + hz, gy = gy0 + hy, gx = gx0 + hx;
            bool ok = ((unsigned)gz < 32u) && ((unsigned)gy < 32u) && ((unsigned)gx < 32u);
            int pg = (gz << 10) + (gy << 5) + gx;
            unsigned chs = (unsigned)((lane & 1) ^ ((hx >> 2) & 1));  // swizzle-inverse
            srcOff[i] = ok ? (unsigned)(128 + (((b << 15) + pg) << 7) + chs * 16)
                           : (unsigned)((lane & 1) * 16);             // zero page
        }
    }

    // ---- per-lane LDS read bases for dx=0..4 (XOR-swizzled) ----
    int axd[5];
    #pragma unroll
    for (int dx = 0; dx < 5; ++dx) {
        int xx = (r & 7) + dx;
        int byte = wv * 4608 + (r >> 3) * 384 + xx * 32 + chslot * 16;
        axd[dx] = byte ^ ((xx & 4) << 2);
    }

    const char* kbl = (const char*)Kb + r * 128 + thalf * 8192 + chslot * 16;

    f32x4 acc[4][4];
    #pragma unroll
    for (int i = 0; i < 4; ++i)
        #pragma unroll
        for (int j = 0; j < 4; ++j) acc[i][j] = (f32x4)0.0f;

    // LDS byte address for tap pair P (this lane's half), compile-time tap math
#define PAIR_ADDR(P)                                                          \
    (thv ? (axd[(((2 * (P) + 1 == 125) ? 124 : 2 * (P) + 1)) % 5]             \
            + ((((2 * (P) + 1 == 125) ? 124 : 2 * (P) + 1)) / 25) * 4608      \
            + (((((2 * (P) + 1 == 125) ? 124 : 2 * (P) + 1)) / 5) % 5) * 384) \
         : (axd[(2 * (P)) % 5] + ((2 * (P)) / 25) * 4608                      \
            + (((2 * (P)) / 5) % 5) * 384))

    // ---- prologue: stage 0 -> buf 0 ----
    {
        const char* ldsb = &xs[wv * 9216];
        #pragma unroll
        for (int i = 0; i < 9; ++i) {
            const char* src = (const char*)xbz + srcOff[i];
            __builtin_amdgcn_global_load_lds(
                (const __attribute__((address_space(1))) unsigned int*)src,
                (__attribute__((address_space(3))) unsigned int*)(ldsb + i * 1024),
                16, 0, 0);
        }
    }
    __syncthreads();

    #pragma unroll 1
    for (int stage = 0; stage < 4; ++stage) {
        // issue next stage's staging first — hides under this stage's MFMAs
        if (stage < 3) {
            const char* ldsb = &xs[((stage + 1) & 1) * 36864 + wv * 9216];
            #pragma unroll
            for (int i = 0; i < 9; ++i) {
                const char* src = (const char*)xbz + srcOff[i] + (stage + 1) * 32;
                __builtin_amdgcn_global_load_lds(
                    (const __attribute__((address_space(1))) unsigned int*)src,
                    (__attribute__((address_space(3))) unsigned int*)(ldsb + i * 1024),
                    16, 0, 0);
            }
        }
        const int bufOff = (stage & 1) * 36864;
        const char* kbs = kbl + stage * 32;

        // Kb ring prefetch: 4 slots, 3 pairs deep (slot (P+3)&3 never = P&3)
        bf16x8 Ab[4][4];
        #pragma unroll
        for (int pf = 0; pf < 3; ++pf)
            #pragma unroll
            for (int mo = 0; mo < 4; ++mo)
                Ab[pf][mo] = *(const bf16x8*)(kbs + pf * 16384 + mo * 2048);

        // LDS B ring: 1 COMPUTE ahead
        bf16x8 xn[2][4];
        {
            int ad = PAIR_ADDR(0) + bufOff;
            #pragma unroll
            for (int np = 0; np < 4; ++np)
                xn[0][np] = *(const bf16x8*)&xs[ad + np * 768];
        }

        #pragma unroll
        for (int P = 0; P < 63; ++P) {
            if (P + 3 < 63) {
                #pragma unroll
                for (int mo = 0; mo < 4; ++mo)
                    Ab[(P + 3) & 3][mo] =
                        *(const bf16x8*)(kbs + (P + 3) * 16384 + mo * 2048);
            }
            if (P + 1 < 63) {
                int ad = PAIR_ADDR(P + 1) + bufOff;
                #pragma unroll
                for (int np = 0; np < 4; ++np)
                    xn[(P + 1) & 1][np] = *(const bf16x8*)&xs[ad + np * 768];
            }
            #pragma unroll
            for (int mo = 0; mo < 4; ++mo)
                #pragma unroll
                for (int np = 0; np < 4; ++np)
                    acc[mo][np] = __builtin_amdgcn_mfma_f32_16x16x32_bf16(
                        Ab[P & 3][mo], xn[P & 1][np], acc[mo][np], 0, 0, 0);
        }
        __syncthreads();
    }
#undef PAIR_ADDR

    // epilogue: D row = o-in-tile = g*4+reg, col = pos-in-tile = r
    const int oz = zt * 4 + wv;
    #pragma unroll
    for (int mo = 0; mo < 4; ++mo) {
        #pragma unroll
        for (int reg = 0; reg < 4; ++reg) {
            int o = mo * 16 + g * 4 + reg;
            float* op = out + (((size_t)(b * 64 + o)) << 15) + (oz << 10);
            #pragma unroll
            for (int np = 0; np < 4; ++np) {
                int ly = np * 2 + (r >> 3), lx = r & 7;
                op[((yt * 8 + ly) << 5) + (xt * 8 + lx)] = 0.1f * acc[mo][np][reg];
            }
        }
    }
}

extern "C" void kernel_launch(void* const* d_in, const int* in_sizes, int n_in,
                              void* d_out, int out_size, void* d_ws, size_t ws_size,
                              hipStream_t stream) {
    const float* x       = (const float*)d_in[0];
    const float* w_lin0  = (const float*)d_in[1];
    const float* w_lin1  = (const float*)d_in[2];
    const float* tp      = (const float*)d_in[3];
    unsigned short* Kb  = (unsigned short*)d_ws;                        // ~1.03 MB
    unsigned short* xbz = (unsigned short*)((char*)d_ws + (2u << 20));  // 128B zeros + 16.8MB bf16 x
    float* out = (float*)d_out;

    build_K<<<126, 256, 0, stream>>>(w_lin0, w_lin1, tp, Kb);
    to_blc<<<512, 256, 0, stream>>>(x, xbz);
    conv_mfma<<<512, 256, 0, stream>>>(xbz, Kb, out);
}

// Round 6
// 267.560 us; speedup vs baseline: 1.3032x; 1.2739x over previous
//
#include <hip/hip_runtime.h>
#include <math.h>

typedef __attribute__((ext_vector_type(8))) short bf16x8;
typedef __attribute__((ext_vector_type(4))) float f32x4;
typedef __attribute__((ext_vector_type(4))) unsigned int u32x4;

#define SGB(mask, n) __builtin_amdgcn_sched_group_barrier((mask), (n), 0)
// masks: MFMA=0x8, VMEM_READ=0x20, DS_READ=0x100

__device__ __forceinline__ unsigned f2bf(float f) {
    union { float f; unsigned u; } v; v.f = f;
    return (v.u + 0x7FFFu + ((v.u >> 16) & 1u)) >> 16;   // RTNE bf16
}

// Build conv kernel in bf16, layout Kb[tap][o][i] (i contiguous), taps 0..125
// with tap 125 all-zero (pad for tap-pairing). Self-interaction folded into
// center tap (62), x10 since out = 0.1*conv_total.
__global__ __launch_bounds__(256) void build_K(
    const float* __restrict__ w_lin0,
    const float* __restrict__ w_lin1,
    const float* __restrict__ tp_weight,
    unsigned short* __restrict__ Kb)
{
    const int tid = (int)threadIdx.x;
    const int tap = (int)blockIdx.x;            // 0..125
    if (tap == 125) {
        for (int n = tid; n < 4096; n += 256) Kb[125 * 4096 + n] = 0;
        return;
    }
    const int i1 = tap / 25, i2 = (tap / 5) % 5, i3 = tap % 5;
    const float X = -1.0f + 0.5f * (float)i1;
    const float Y = -1.0f + 0.5f * (float)i2;
    const float Z = -1.0f + 0.5f * (float)i3;
    const float d = sqrtf(X*X + Y*Y + Z*Z);
    const float dinv = 1.0f / fmaxf(d, 1e-12f);
    const float vx = X * dinv, vy = Y * dinv, vz = Z * dinv;
    const float r2 = vx*vx + vy*vy + vz*vz;

    __shared__ float wsh[1280];
    __shared__ float y1s[3];
    __shared__ float Qs[9];

    if (tid == 0) {
        const float s3 = 1.7320508075688772f;
        const float s15 = 3.872983346207417f;
        y1s[0] = s3 * vy; y1s[1] = s3 * vz; y1s[2] = s3 * vx;
        float y2v0 = s15 * vx * vy;
        float y2v1 = s15 * vy * vz;
        float y2v2 = 1.118033988749895f * (3.0f * vz * vz - r2);
        float y2v3 = s15 * vx * vz;
        float y2v4 = 1.9364916731037085f * (vx * vx - vy * vy);
        const float INV10 = 0.31622776601683794f;
        const float INV30 = 0.18257418583505536f;
        Qs[0] = -y2v2 * INV30 - y2v4 * INV10;
        Qs[4] =  2.0f * y2v2 * INV30;
        Qs[8] = -y2v2 * INV30 + y2v4 * INV10;
        Qs[1] = Qs[3] = y2v1 * INV10;
        Qs[2] = Qs[6] = y2v0 * INV10;
        Qs[5] = Qs[7] = y2v3 * INV10;
    }

    float emb[5];
    #pragma unroll
    for (int e = 0; e < 5; ++e) {
        float t = (d - 0.25f * (float)e) * 4.0f;
        emb[e] = expf(-t * t) * (1.0f / 1.12f);
    }
    const float scale = cosf(3.14159265358979323846f * d) / 11.180339887498949f;

    for (int j = tid; j < 1280; j += 256) {
        float s = 0.0f;
        #pragma unroll
        for (int e = 0; e < 5; ++e) s += emb[e] * tp_weight[e * 1280 + j];
        wsh[j] = scale * s;
    }
    __syncthreads();

    const float F0   = 0.17677669529663687f;
    const float F1   = 0.25f;
    const float F0S3 = 0.10206207261596574f;
    const float F1S3 = 0.14433756729740646f;

    #pragma unroll 1
    for (int n = 0; n < 16; ++n) {
        int e = n * 256 + tid;
        int o = e & 63, i = e >> 6;
        float Kv;
        if (o < 16) {
            if (i < 16) {
                Kv = F0 * wsh[0 * 256 + i * 16 + o];
            } else {
                int u = (i - 16) / 3, a = (i - 16) % 3;
                Kv = F0S3 * y1s[a] * wsh[3 * 256 + u * 16 + o];
            }
        } else {
            int wcol = (o - 16) / 3, c = (o - 16) % 3;
            if (i < 16) {
                Kv = F1S3 * y1s[c] * wsh[1 * 256 + i * 16 + wcol];
            } else {
                int u = (i - 16) / 3, a = (i - 16) % 3;
                Kv = F1 * Qs[a * 3 + c] * wsh[4 * 256 + u * 16 + wcol];
                if (a == c) Kv += F1S3 * wsh[2 * 256 + u * 16 + wcol];
            }
        }
        if (tap == 62) {
            if (o < 16) {
                if (i < 16) Kv += 2.5f * w_lin0[i * 16 + o];
            } else if (i >= 16) {
                int v = (o - 16) / 3, m = (o - 16) % 3;
                int u = (i - 16) / 3, a = (i - 16) % 3;
                if (a == m) Kv += 2.5f * w_lin1[u * 16 + v];
            }
        }
        Kb[(tap * 64 + o) * 64 + i] = (unsigned short)f2bf(Kv);
    }
}

// Pre-pass: x fp32 [b][c][32^3] -> xbz bf16 channel-last [b][pos][64ch],
// preceded by a 128B zero page (for OOB halo lanes).
__global__ __launch_bounds__(256) void to_blc(
    const float* __restrict__ x,
    unsigned short* __restrict__ xbz)
{
    const int tid = (int)threadIdx.x, blk = (int)blockIdx.x;
    if (blk == 0 && tid < 64) xbz[tid] = 0;          // zero page
    const int p = blk * 256 + tid;                   // 0..131071
    const int b = p >> 15, pos = p & 32767;
    const float* xp = x + ((size_t)b << 21) + pos;
    unsigned short* op = xbz + 64 + (size_t)p * 64;
    #pragma unroll
    for (int cg = 0; cg < 8; ++cg) {
        u32x4 dv;
        #pragma unroll
        for (int jj = 0; jj < 4; ++jj) {
            float f0 = xp[((size_t)(cg * 8 + 2 * jj)) << 15];
            float f1 = xp[((size_t)(cg * 8 + 2 * jj + 1)) << 15];
            dv[jj] = f2bf(f0) | (f2bf(f1) << 16);
        }
        *(u32x4*)(op + cg * 8) = dv;
    }
}

// Implicit-GEMM conv via MFMA 16x16x32 bf16.
// Block: 256 thr = 4 waves; tile = 4z x 8y x 8x = 256 pos, all 64 o.
// LDS: double-buffered halo tile, XOR-16 swizzle, global_load_lds staging.
// Pipeline pinned with sched_group_barrier: per iteration
// {4 VMEM_READ (Ab, P+3)} {4 DS_READ (xn, P+2)} {16 MFMA (P)} — the round-5
// compiler sank all prefetches to use (VGPR=108), serializing load latency.
__global__ __launch_bounds__(256, 2) void conv_mfma(
    const unsigned short* __restrict__ xbz,
    const unsigned short* __restrict__ Kb,
    float* __restrict__ out)
{
    __shared__ __align__(16) char xs[73728];   // 2 x 36864

    const int tid = (int)threadIdx.x;
    const int blk = (int)blockIdx.x;
    const int xt = blk & 3, yt = (blk >> 2) & 3, zt = (blk >> 4) & 7, b = blk >> 7;
    const int lane = tid & 63, wv = tid >> 6;
    const int r = lane & 15, g = lane >> 4;
    const int thalf = g >> 1, chslot = g & 1;
    const bool thv = (thalf != 0);

    // ---- staging source offsets (9 chunks/thread), computed once ----
    unsigned srcOff[9];
    {
        const int gz0 = zt * 4 - 2, gy0 = yt * 8 - 2, gx0 = xt * 8 - 2;
        #pragma unroll
        for (int i = 0; i < 9; ++i) {
            int pos = wv * 288 + i * 32 + (lane >> 1);     // 0..1151
            int hz = pos / 144; int rem = pos - hz * 144;
            int hy = rem / 12;  int hx = rem - hy * 12;
            int gz = gz0 + hz, gy = gy0 + hy, gx = gx0 + hx;
            bool ok = ((unsigned)gz < 32u) && ((unsigned)gy < 32u) && ((unsigned)gx < 32u);
            int pg = (gz << 10) + (gy << 5) + gx;
            unsigned chs = (unsigned)((lane & 1) ^ ((hx >> 2) & 1));  // swizzle-inverse
            srcOff[i] = ok ? (unsigned)(128 + (((b << 15) + pg) << 7) + chs * 16)
                           : (unsigned)((lane & 1) * 16);             // zero page
        }
    }

    // ---- per-lane LDS read bases for dx=0..4 (XOR-swizzled) ----
    int axd[5];
    #pragma unroll
    for (int dx = 0; dx < 5; ++dx) {
        int xx = (r & 7) + dx;
        int byte = wv * 4608 + (r >> 3) * 384 + xx * 32 + chslot * 16;
        axd[dx] = byte ^ ((xx & 4) << 2);
    }

    const char* kbl = (const char*)Kb + r * 128 + thalf * 8192 + chslot * 16;

    f32x4 acc[4][4];
    #pragma unroll
    for (int i = 0; i < 4; ++i)
        #pragma unroll
        for (int j = 0; j < 4; ++j) acc[i][j] = (f32x4)0.0f;

    // LDS byte address for tap pair P (this lane's half), compile-time tap math
#define PAIR_ADDR(P)                                                          \
    (thv ? (axd[(((2 * (P) + 1 == 125) ? 124 : 2 * (P) + 1)) % 5]             \
            + ((((2 * (P) + 1 == 125) ? 124 : 2 * (P) + 1)) / 25) * 4608      \
            + (((((2 * (P) + 1 == 125) ? 124 : 2 * (P) + 1)) / 5) % 5) * 384) \
         : (axd[(2 * (P)) % 5] + ((2 * (P)) / 25) * 4608                      \
            + (((2 * (P)) / 5) % 5) * 384))

    // ---- prologue: stage 0 -> buf 0 ----
    {
        const char* ldsb = &xs[wv * 9216];
        #pragma unroll
        for (int i = 0; i < 9; ++i) {
            const char* src = (const char*)xbz + srcOff[i];
            __builtin_amdgcn_global_load_lds(
                (const __attribute__((address_space(1))) unsigned int*)src,
                (__attribute__((address_space(3))) unsigned int*)(ldsb + i * 1024),
                16, 0, 0);
        }
    }
    __syncthreads();

    #pragma unroll 1
    for (int stage = 0; stage < 4; ++stage) {
        const int bufOff = (stage & 1) * 36864;
        const char* kbs = kbl + stage * 32;

        // ring prologues for THIS stage first (so Ab waits don't FIFO-wait
        // on the staging DMAs issued below)
        bf16x8 Ab[4][4];
        #pragma unroll
        for (int pf = 0; pf < 3; ++pf)
            #pragma unroll
            for (int mo = 0; mo < 4; ++mo)
                Ab[pf][mo] = *(const bf16x8*)(kbs + pf * 16384 + mo * 2048);
        SGB(0x20, 12);

        bf16x8 xn[3][4];
        {
            int ad0 = PAIR_ADDR(0) + bufOff;
            int ad1 = PAIR_ADDR(1) + bufOff;
            #pragma unroll
            for (int np = 0; np < 4; ++np)
                xn[0][np] = *(const bf16x8*)&xs[ad0 + np * 768];
            #pragma unroll
            for (int np = 0; np < 4; ++np)
                xn[1][np] = *(const bf16x8*)&xs[ad1 + np * 768];
        }
        SGB(0x100, 8);

        // issue next stage's staging — hides under this stage's MFMAs
        if (stage < 3) {
            const char* ldsb = &xs[((stage + 1) & 1) * 36864 + wv * 9216];
            #pragma unroll
            for (int i = 0; i < 9; ++i) {
                const char* src = (const char*)xbz + srcOff[i] + (stage + 1) * 32;
                __builtin_amdgcn_global_load_lds(
                    (const __attribute__((address_space(1))) unsigned int*)src,
                    (__attribute__((address_space(3))) unsigned int*)(ldsb + i * 1024),
                    16, 0, 0);
            }
            SGB(0x20, 9);
        }

        #pragma unroll
        for (int P = 0; P < 63; ++P) {
            if (P < 60) {
                #pragma unroll
                for (int mo = 0; mo < 4; ++mo)
                    Ab[(P + 3) & 3][mo] =
                        *(const bf16x8*)(kbs + (P + 3) * 16384 + mo * 2048);
                SGB(0x20, 4);
            }
            if (P < 61) {
                int ad = PAIR_ADDR(P + 2) + bufOff;
                #pragma unroll
                for (int np = 0; np < 4; ++np)
                    xn[(P + 2) % 3][np] = *(const bf16x8*)&xs[ad + np * 768];
                SGB(0x100, 4);
            }
            #pragma unroll
            for (int mo = 0; mo < 4; ++mo)
                #pragma unroll
                for (int np = 0; np < 4; ++np)
                    acc[mo][np] = __builtin_amdgcn_mfma_f32_16x16x32_bf16(
                        Ab[P & 3][mo], xn[P % 3][np], acc[mo][np], 0, 0, 0);
            SGB(0x8, 16);
        }
        __syncthreads();
    }
#undef PAIR_ADDR

    // epilogue: D row = o-in-tile = g*4+reg, col = pos-in-tile = r
    const int oz = zt * 4 + wv;
    #pragma unroll
    for (int mo = 0; mo < 4; ++mo) {
        #pragma unroll
        for (int reg = 0; reg < 4; ++reg) {
            int o = mo * 16 + g * 4 + reg;
            float* op = out + (((size_t)(b * 64 + o)) << 15) + (oz << 10);
            #pragma unroll
            for (int np = 0; np < 4; ++np) {
                int ly = np * 2 + (r >> 3), lx = r & 7;
                op[((yt * 8 + ly) << 5) + (xt * 8 + lx)] = 0.1f * acc[mo][np][reg];
            }
        }
    }
}

extern "C" void kernel_launch(void* const* d_in, const int* in_sizes, int n_in,
                              void* d_out, int out_size, void* d_ws, size_t ws_size,
                              hipStream_t stream) {
    const float* x       = (const float*)d_in[0];
    const float* w_lin0  = (const float*)d_in[1];
    const float* w_lin1  = (const float*)d_in[2];
    const float* tp      = (const float*)d_in[3];
    unsigned short* Kb  = (unsigned short*)d_ws;                        // ~1.03 MB
    unsigned short* xbz = (unsigned short*)((char*)d_ws + (2u << 20));  // 128B zeros + 16.8MB bf16 x
    float* out = (float*)d_out;

    build_K<<<126, 256, 0, stream>>>(w_lin0, w_lin1, tp, Kb);
    to_blc<<<512, 256, 0, stream>>>(x, xbz);
    conv_mfma<<<512, 256, 0, stream>>>(xbz, Kb, out);
}